// Round 9
// baseline (734.747 us; speedup 1.0000x reference)
//
#include <hip/hip_runtime.h>

#define BIGF 100000000.0f
#define LOG2E 1.4426950408889634f
#define LN2f 0.6931471805599453f
constexpr int BATCH = 64;
constexpr int T = 512;     // N == M == 512
constexpr int DIMS = 64;

constexpr int SS = 12;     // diagonals per superstep (even, matches all parities)
constexpr int RING = 24;   // 2 supersteps of slots
constexpr int PADF = 512;  // guard pad before ring
constexpr int NSS = 86;    // ceil(1023 / 12)

#if __has_builtin(__builtin_amdgcn_exp2f)
#define EXP2F(x) __builtin_amdgcn_exp2f(x)
#else
#define EXP2F(x) __expf((x) * LN2f)
#endif
#if __has_builtin(__builtin_amdgcn_logf)
#define LOG2F(x) __builtin_amdgcn_logf(x)
#else
#define LOG2F(x) (__logf(x) * LOG2E)
#endif

// lane l <- lane l-1, lane 0 <- lane 63 (full-wave rotate right by 1).
#if __has_builtin(__builtin_amdgcn_update_dpp)
#define ROTL1(x) __int_as_float(__builtin_amdgcn_update_dpp(               \
    0, __float_as_int(x), 0x13C, 0xF, 0xF, 1))
#else
#define ROTL1(x) __int_as_float(__builtin_amdgcn_ds_bpermute(              \
    rot_addr, __float_as_int(x)))
#endif

// ---------------------------------------------------------------------------
// Kernel A: pairwise squared distances, DIAGONAL-PACKED, pre-scaled by log2e.
// Diagonal d (d = i + j, i,j in [1,T]):
//   d <= T+1: lo = 1,   off = (d-2)(d-1)/2
//   else:     lo = d-T, off = T*T - (2T+1-d)(2T+2-d)/2
// Cell (i, d-i) stored at off + (i - lo).  Total exactly T*T floats.
// ---------------------------------------------------------------------------
__global__ __launch_bounds__(256) void pairdist_diag_kernel(
    const float* __restrict__ x, const float* __restrict__ y,
    float* __restrict__ D) {
  int bid = blockIdx.x;
  int b = bid >> 6;          // 64 tiles per batch
  int tile = bid & 63;
  int n0 = (tile >> 3) << 6;
  int m0 = (tile & 7) << 6;

  __shared__ float xs[64][65];
  __shared__ float ys[64][65];
  __shared__ float stage[64][66];
  __shared__ float x2s[64], y2s[64];

  const float* xb = x + ((size_t)b * T + n0) * DIMS;
  const float* yb = y + ((size_t)b * T + m0) * DIMS;
  int tid = threadIdx.x;

  for (int e = tid; e < 64 * 64; e += 256) {
    int r = e >> 6, c = e & 63;
    xs[r][c] = xb[(size_t)r * DIMS + c];
    ys[r][c] = yb[(size_t)r * DIMS + c];
  }
  __syncthreads();

  if (tid < 64) {
    float s = 0.f;
    #pragma unroll
    for (int k = 0; k < 64; ++k) { float v = xs[tid][k]; s += v * v; }
    x2s[tid] = s;
  } else if (tid < 128) {
    int r = tid - 64;
    float s = 0.f;
    #pragma unroll
    for (int k = 0; k < 64; ++k) { float v = ys[r][k]; s += v * v; }
    y2s[r] = s;
  }
  __syncthreads();

  int tr = tid >> 4, tc = tid & 15;
  int r0 = tr * 4, c0 = tc * 4;
  float acc[4][4] = {};
  #pragma unroll 8
  for (int k = 0; k < 64; ++k) {
    float a0 = xs[r0 + 0][k], a1 = xs[r0 + 1][k];
    float a2 = xs[r0 + 2][k], a3 = xs[r0 + 3][k];
    float b0 = ys[c0 + 0][k], b1 = ys[c0 + 1][k];
    float b2 = ys[c0 + 2][k], b3 = ys[c0 + 3][k];
    acc[0][0] += a0 * b0; acc[0][1] += a0 * b1; acc[0][2] += a0 * b2; acc[0][3] += a0 * b3;
    acc[1][0] += a1 * b0; acc[1][1] += a1 * b1; acc[1][2] += a1 * b2; acc[1][3] += a1 * b3;
    acc[2][0] += a2 * b0; acc[2][1] += a2 * b1; acc[2][2] += a2 * b2; acc[2][3] += a2 * b3;
    acc[3][0] += a3 * b0; acc[3][1] += a3 * b1; acc[3][2] += a3 * b2; acc[3][3] += a3 * b3;
  }

  #pragma unroll
  for (int r = 0; r < 4; ++r) {
    float xn = x2s[r0 + r];
    #pragma unroll
    for (int c = 0; c < 4; ++c)
      stage[r0 + r][c0 + c] = (xn + y2s[c0 + c] - 2.f * acc[r][c]) * LOG2E;
  }
  __syncthreads();

  float* Dp = D + (size_t)b * (T * T);
  int p = tid & 63;
  int sub = __builtin_amdgcn_readfirstlane(tid >> 6);
  int ldsoff = 65 * p;
  #pragma unroll 1
  for (int t = sub; t <= 126; t += 4) {
    int rlo = (t > 63) ? t - 63 : 0;
    int rhi = (t < 63) ? t : 63;
    int d = n0 + m0 + t + 2;
    int lo = (d <= T + 1) ? 1 : d - T;
    int off = (d <= T + 1) ? (((d - 2) * (d - 1)) >> 1)
                           : (T * T - (((2 * T + 1 - d) * (2 * T + 2 - d)) >> 1));
    int r = rlo + p;
    if (r <= rhi) {
      float v = ((const float*)stage)[ldsoff + 65 * rlo + t];  // stage[r][t-r]
      Dp[off + (n0 + r + 1 - lo)] = v;
    }
  }
}

// ---------------------------------------------------------------------------
// Kernel B v2: producer/consumer DP, slim consumer.
//  - klo/khi slot guards back (avg 4.5/8 active): wave-uniform SALU branches.
//  - rotation reuse: dg at diag d == patched ror(R[d-2]) == the "up" computed
//    at d-1, carried in ping-pong UPa/UPb.  One rotation set per diagonal.
//  - 2-array DP state (A/Bv ping-pong): R[d-2] is dead once its rotation is
//    carried.  d==2's R[0][0]=0 seed folds into UPa's init.
// ---------------------------------------------------------------------------
#define ISSUE(BANK, slot_, dd_)                                               \
  {                                                                           \
    const int di = (dd_);                                                     \
    if (di <= 2 * T) {                                                        \
      const int lo_  = (di <= T + 1) ? 1 : di - T;                            \
      const int hi_  = (di - 1 < T) ? di - 1 : T;                             \
      const int klo_ = (lo_ - 1) >> 6;                                        \
      const int khi_ = (hi_ - 1) >> 6;                                        \
      const float* sp = &lds[PADF + (slot_) * T + 1 - lo_];                   \
      _Pragma("unroll")                                                       \
      for (int k = 0; k < 8; ++k)                                             \
        if (k >= klo_ && k <= khi_) BANK[k] = sp[(k << 6) + lane];            \
    }                                                                         \
  }

#define STEP(dd_, RP1, ROUT, BANK, UPIN, UPOUT)                               \
  {                                                                           \
    const int dd = (dd_);                                                     \
    if (dd <= 2 * T) {                                                        \
      const int lo  = (dd <= T + 1) ? 1 : dd - T;                             \
      const int hi  = (dd - 1 < T) ? dd - 1 : T;                              \
      const int klo = (lo - 1) >> 6;                                          \
      const int khi = (hi - 1) >> 6;                                          \
      const int krot = (klo > 0) ? klo - 1 : 0;                               \
      float ror1[8];                                                          \
      _Pragma("unroll")                                                       \
      for (int k = 0; k < 8; ++k)                                             \
        if (k >= krot && k <= khi) ror1[k] = ROTL1(RP1[k]);                   \
      _Pragma("unroll")                                                       \
      for (int k = 0; k < 8; ++k)                                             \
        if (k >= klo && k <= khi) {                                           \
          UPOUT[k] = lz ? ((k == 0) ? BIGF : ror1[k - 1]) : ror1[k];          \
          const float up  = UPOUT[k];                                         \
          const float dgv = UPIN[k];                                          \
          const float lf  = RP1[k];                                           \
          const float mn  = fminf(fminf(up, lf), dgv);                        \
          const float md  = __builtin_amdgcn_fmed3f(up, lf, dgv);             \
          const float mx  = fmaxf(fmaxf(up, lf), dgv);                        \
          const float sv  = 1.0f + EXP2F(mn - md) + EXP2F(mn - mx);           \
          const float val = BANK[k] + mn - LOG2F(sv);                         \
          const int su = dd - (k << 6) - 2;                                   \
          const unsigned ju = (unsigned)(su - lane);                          \
          ROUT[k] = (ju < (unsigned)T) ? val : BIGF;                          \
        }                                                                     \
    }                                                                         \
  }

#define FILLSS(ss_)                                                           \
  {                                                                           \
    const int ssv = (ss_);                                                    \
    if (ssv < NSS) {                                                          \
      const int d0n = 2 + SS * ssv;                                           \
      const int halfn = (ssv & 1) * SS;                                       \
      for (int tt = wave - 1; tt < SS; tt += 4) {                             \
        const int d = d0n + tt;                                               \
        if (d <= 2 * T) {                                                     \
          const int off = (d <= T + 1)                                        \
              ? (((d - 2) * (d - 1)) >> 1)                                    \
              : (T * T - (((2 * T + 1 - d) * (2 * T + 2 - d)) >> 1));         \
          float* dst = &lds[PADF + (halfn + tt) * T];                         \
          _Pragma("unroll")                                                   \
          for (int u = 0; u < 8; ++u) {                                       \
            int gi = off + (u << 6) + lane;                                   \
            gi = (gi > T * T - 1) ? (T * T - 1) : gi;                         \
            dst[(u << 6) + lane] = Db[gi];                                    \
          }                                                                   \
        }                                                                     \
      }                                                                       \
    }                                                                         \
  }

__global__ __launch_bounds__(320, 1) void dp_ring_kernel(const float* __restrict__ D,
                                                         float* __restrict__ out) {
  const int b = blockIdx.x;
  const int tid = threadIdx.x;
  const int wave = tid >> 6;   // 0 = consumer, 1..4 = producers
  const int lane = tid & 63;
  const bool lz = (lane == 0);
  const float* __restrict__ Db = D + (size_t)b * (T * T);
#if !__has_builtin(__builtin_amdgcn_update_dpp)
  const int rot_addr = ((lane + 63) & 63) << 2;
#endif

  __shared__ float lds[PADF + RING * T];  // ~50 KB

  float A[8], Bv[8], UPa[8], UPb[8], pcE[8], pcO[8];
  #pragma unroll
  for (int k = 0; k < 8; ++k) {
    A[k] = BIGF; Bv[k] = BIGF; UPa[k] = BIGF; UPb[k] = BIGF;
  }
  UPa[0] = lz ? 0.0f : BIGF;   // dg seed: R[0][0] = 0 at d == 2

  // pre-fill guard pad (boundary-slot reads can dip below the ring; must be
  // finite so NaN garbage never feeds exp/log even on discarded lanes)
  for (int e = tid; e < PADF; e += 320) lds[e] = BIGF;

  if (wave > 0) FILLSS(0)
  __syncthreads();

  #pragma unroll 1
  for (int s = 0; s < NSS; ++s) {
    if (wave == 0) {
      const int d0 = 2 + SS * s;
      const int half = (s & 1) * SS;
      ISSUE(pcE, half + 0, d0 + 0)
      ISSUE(pcO, half + 1, d0 + 1)
      STEP(d0 + 0,  Bv, A, pcE, UPa, UPb)
      ISSUE(pcE, half + 2, d0 + 2)
      STEP(d0 + 1,  A, Bv, pcO, UPb, UPa)
      ISSUE(pcO, half + 3, d0 + 3)
      STEP(d0 + 2,  Bv, A, pcE, UPa, UPb)
      ISSUE(pcE, half + 4, d0 + 4)
      STEP(d0 + 3,  A, Bv, pcO, UPb, UPa)
      ISSUE(pcO, half + 5, d0 + 5)
      STEP(d0 + 4,  Bv, A, pcE, UPa, UPb)
      ISSUE(pcE, half + 6, d0 + 6)
      STEP(d0 + 5,  A, Bv, pcO, UPb, UPa)
      ISSUE(pcO, half + 7, d0 + 7)
      STEP(d0 + 6,  Bv, A, pcE, UPa, UPb)
      ISSUE(pcE, half + 8, d0 + 8)
      STEP(d0 + 7,  A, Bv, pcO, UPb, UPa)
      ISSUE(pcO, half + 9, d0 + 9)
      STEP(d0 + 8,  Bv, A, pcE, UPa, UPb)
      ISSUE(pcE, half + 10, d0 + 10)
      STEP(d0 + 9,  A, Bv, pcO, UPb, UPa)
      ISSUE(pcO, half + 11, d0 + 11)
      STEP(d0 + 10, Bv, A, pcE, UPa, UPb)
      STEP(d0 + 11, A, Bv, pcO, UPb, UPa)
    } else {
      FILLSS(s + 1)
    }
    __syncthreads();
  }

  // diag 1024 computed at s=85, t=2 (even phase) -> ROUT = A.
  // R'(512,512) = slot 7, lane 63.  Unscale by ln2.
  if (tid == 63) atomicAdd(out, A[7] * (LN2f / BATCH));
}

// ---------------------------------------------------------------------------
// Fallback (ws too small): fused on-the-fly DP (round-2 version, known good).
// ---------------------------------------------------------------------------
__global__ __launch_bounds__(512) void dp_onfly_kernel(
    const float* __restrict__ x, const float* __restrict__ y,
    float* __restrict__ out) {
  int b = blockIdx.x;
  int tid = threadIdx.x;
  int i = tid + 1;

  __shared__ float ys[T][DIMS + 1];
  __shared__ float y2s[T];
  __shared__ float rbuf[3][T + 1];

  const float* yb = y + (size_t)b * T * DIMS;
  for (int e = tid; e < T * DIMS; e += 512) {
    int r = e >> 6, c = e & 63;
    ys[r][c] = yb[e];
  }
  for (int e = tid; e < 3 * (T + 1); e += 512) ((float*)rbuf)[e] = BIGF;
  __syncthreads();
  if (tid == 0) rbuf[0][0] = 0.f;
  {
    float s = 0.f;
    #pragma unroll
    for (int k = 0; k < DIMS; ++k) { float v = ys[tid][k]; s += v * v; }
    y2s[tid] = s;
  }

  float xr[DIMS];
  float x2 = 0.f;
  const float* xb = x + ((size_t)b * T + (i - 1)) * DIMS;
  #pragma unroll
  for (int k = 0; k < DIMS; ++k) { xr[k] = xb[k]; x2 += xr[k] * xr[k]; }
  __syncthreads();

  float* rp2 = rbuf[0];
  float* rp1 = rbuf[1];
  float* rc  = rbuf[2];

  float val = BIGF;
  for (int d = 2; d <= 2 * T; ++d) {
    int j = d - i;
    bool valid = (j >= 1) && (j <= T);
    float cost = 0.f;
    if (valid) {
      float dot = 0.f;
      #pragma unroll
      for (int k = 0; k < DIMS; ++k) dot += xr[k] * ys[j - 1][k];
      cost = x2 + y2s[j - 1] - 2.f * dot;
    }
    float a = rp1[i - 1];
    float bb = rp1[i];
    float c = rp2[i - 1];
    float m = fminf(fminf(a, bb), c);
    float s = __expf(m - a) + __expf(m - bb) + __expf(m - c);
    val = valid ? (cost + m - __logf(s)) : BIGF;
    rc[i] = val;
    if (tid == 0) rc[0] = BIGF;
    __syncthreads();
    float* tmp = rp2; rp2 = rp1; rp1 = rc; rc = tmp;
  }

  if (tid == T - 1) atomicAdd(out, val * (1.0f / BATCH));
}

extern "C" void kernel_launch(void* const* d_in, const int* in_sizes, int n_in,
                              void* d_out, int out_size, void* d_ws, size_t ws_size,
                              hipStream_t stream) {
  const float* x = (const float*)d_in[0];   // inputs  (B,T,D)
  const float* y = (const float*)d_in[1];   // targets (B,T,D)
  float* out = (float*)d_out;

  hipMemsetAsync(d_out, 0, sizeof(float), stream);

  size_t needD = (size_t)BATCH * T * T * sizeof(float);  // 64 MiB
  if (ws_size >= needD) {
    float* Dw = (float*)d_ws;
    pairdist_diag_kernel<<<BATCH * 64, 256, 0, stream>>>(x, y, Dw);
    dp_ring_kernel<<<BATCH, 320, 0, stream>>>(Dw, out);
  } else {
    dp_onfly_kernel<<<BATCH, 512, 0, stream>>>(x, y, out);
  }
}

// Round 10
// 460.298 us; speedup vs baseline: 1.5962x; 1.5962x over previous
//
#include <hip/hip_runtime.h>

#define BIGF 100000000.0f
#define LOG2E 1.4426950408889634f
#define LN2f 0.6931471805599453f
constexpr int BATCH = 64;
constexpr int T = 512;     // N == M == 512
constexpr int DIMS = 64;

constexpr int SS = 16;     // diagonals per superstep (even)
constexpr int NSS = 64;    // 64 x 16 = 1024 diagonals: d = 2 .. 1025

#if __has_builtin(__builtin_amdgcn_exp2f)
#define EXP2F(x) __builtin_amdgcn_exp2f(x)
#else
#define EXP2F(x) __expf((x) * LN2f)
#endif
#if __has_builtin(__builtin_amdgcn_logf)
#define LOG2F(x) __builtin_amdgcn_logf(x)
#else
#define LOG2F(x) (__logf(x) * LOG2E)
#endif

// lane l <- lane l-1, lane 0 <- lane 63 (full-wave rotate right by 1).
#if __has_builtin(__builtin_amdgcn_update_dpp)
#define ROTL1(x) __int_as_float(__builtin_amdgcn_update_dpp(               \
    0, __float_as_int(x), 0x13C, 0xF, 0xF, 1))
#else
#define ROTL1(x) __int_as_float(__builtin_amdgcn_ds_bpermute(              \
    rot_addr, __float_as_int(x)))
#endif

// ---------------------------------------------------------------------------
// Kernel A: pairwise squared distances, DIAGONAL-PACKED, pre-scaled by log2e.
// Diagonal d (d = i + j, i,j in [1,T]):
//   d <= T+1: lo = 1,   off = (d-2)(d-1)/2
//   else:     lo = d-T, off = T*T - (2T+1-d)(2T+2-d)/2
// Cell (i, d-i) stored at off + (i - lo).  Total exactly T*T floats.
// ---------------------------------------------------------------------------
__global__ __launch_bounds__(256) void pairdist_diag_kernel(
    const float* __restrict__ x, const float* __restrict__ y,
    float* __restrict__ D) {
  int bid = blockIdx.x;
  int b = bid >> 6;          // 64 tiles per batch
  int tile = bid & 63;
  int n0 = (tile >> 3) << 6;
  int m0 = (tile & 7) << 6;

  __shared__ float xs[64][65];
  __shared__ float ys[64][65];
  __shared__ float stage[64][66];
  __shared__ float x2s[64], y2s[64];

  const float* xb = x + ((size_t)b * T + n0) * DIMS;
  const float* yb = y + ((size_t)b * T + m0) * DIMS;
  int tid = threadIdx.x;

  for (int e = tid; e < 64 * 64; e += 256) {
    int r = e >> 6, c = e & 63;
    xs[r][c] = xb[(size_t)r * DIMS + c];
    ys[r][c] = yb[(size_t)r * DIMS + c];
  }
  __syncthreads();

  if (tid < 64) {
    float s = 0.f;
    #pragma unroll
    for (int k = 0; k < 64; ++k) { float v = xs[tid][k]; s += v * v; }
    x2s[tid] = s;
  } else if (tid < 128) {
    int r = tid - 64;
    float s = 0.f;
    #pragma unroll
    for (int k = 0; k < 64; ++k) { float v = ys[r][k]; s += v * v; }
    y2s[r] = s;
  }
  __syncthreads();

  int tr = tid >> 4, tc = tid & 15;
  int r0 = tr * 4, c0 = tc * 4;
  float acc[4][4] = {};
  #pragma unroll 8
  for (int k = 0; k < 64; ++k) {
    float a0 = xs[r0 + 0][k], a1 = xs[r0 + 1][k];
    float a2 = xs[r0 + 2][k], a3 = xs[r0 + 3][k];
    float b0 = ys[c0 + 0][k], b1 = ys[c0 + 1][k];
    float b2 = ys[c0 + 2][k], b3 = ys[c0 + 3][k];
    acc[0][0] += a0 * b0; acc[0][1] += a0 * b1; acc[0][2] += a0 * b2; acc[0][3] += a0 * b3;
    acc[1][0] += a1 * b0; acc[1][1] += a1 * b1; acc[1][2] += a1 * b2; acc[1][3] += a1 * b3;
    acc[2][0] += a2 * b0; acc[2][1] += a2 * b1; acc[2][2] += a2 * b2; acc[2][3] += a2 * b3;
    acc[3][0] += a3 * b0; acc[3][1] += a3 * b1; acc[3][2] += a3 * b2; acc[3][3] += a3 * b3;
  }

  #pragma unroll
  for (int r = 0; r < 4; ++r) {
    float xn = x2s[r0 + r];
    #pragma unroll
    for (int c = 0; c < 4; ++c)
      stage[r0 + r][c0 + c] = (xn + y2s[c0 + c] - 2.f * acc[r][c]) * LOG2E;
  }
  __syncthreads();

  float* Dp = D + (size_t)b * (T * T);
  int p = tid & 63;
  int sub = __builtin_amdgcn_readfirstlane(tid >> 6);
  int ldsoff = 65 * p;
  #pragma unroll 1
  for (int t = sub; t <= 126; t += 4) {
    int rlo = (t > 63) ? t - 63 : 0;
    int rhi = (t < 63) ? t : 63;
    int d = n0 + m0 + t + 2;
    int lo = (d <= T + 1) ? 1 : d - T;
    int off = (d <= T + 1) ? (((d - 2) * (d - 1)) >> 1)
                           : (T * T - (((2 * T + 1 - d) * (2 * T + 2 - d)) >> 1));
    int r = rlo + p;
    if (r <= rhi) {
      float v = ((const float*)stage)[ldsoff + 65 * rlo + t];  // stage[r][t-r]
      Dp[off + (n0 + r + 1 - lo)] = v;
    }
  }
}

// ---------------------------------------------------------------------------
// Kernel B v3: producer/consumer DP, BRANCHLESS consumer.
//  - contiguous row mapping: lane l owns rows 8l+1..8l+8 (slot k = row
//    8l+k+1).  up/diag for k>0 are own-lane registers; only k=0 crosses
//    lanes: 2 DPP + 2 patches per diagonal (vs 16+16 strided).
//  - cells descending k: 2-array ping-pong (A even diags, Bv odd).
//  - validity guards GONE: producers BIG-pad out-of-band positions in each
//    512-wide slot.  Junk cells self-propagate as >=1e8 and softmin ignores
//    them (exp2(x - 1e8) == 0), so valid cells are bit-identical.
//  - SS=16, 64 supersteps cover d = 2..1025 exactly (1025 is a junk diag
//    that only writes the odd array; R[1024] lives in A).  Zero runtime
//    branches inside the consumer superstep.
//  - costs: row-indexed LDS slots; consumer reads its 8 rows via 2x
//    ds_read_b128 per slot, all 16 slots loaded as one straight-line block
//    right after the barrier (cb[16][2] float4s) so counted lgkmcnt hides
//    the LDS latency under compute.
// ---------------------------------------------------------------------------
#define CELL(up_, dg_, lf_, cost_, out_)                                      \
  {                                                                           \
    const float up = (up_), dgv = (dg_), lf = (lf_);                          \
    const float mn = fminf(fminf(up, lf), dgv);                               \
    const float md = __builtin_amdgcn_fmed3f(up, lf, dgv);                    \
    const float mx = fmaxf(fmaxf(up, lf), dgv);                               \
    const float sv = 1.0f + EXP2F(mn - md) + EXP2F(mn - mx);                  \
    (out_) = (cost_) + mn - LOG2F(sv);                                        \
  }

#define DTWSTEP(t_, RP2, RP1)                                                 \
  {                                                                           \
    const float rotUp = ROTL1(RP1[7]);                                        \
    const float rotDg = ROTL1(RP2[7]);                                        \
    const float up0 = lz ? BIGF : rotUp;                                      \
    const float dg0 = lz ? (((t_) == 0) ? dseed : BIGF) : rotDg;              \
    CELL(RP1[6], RP2[6], RP1[7], cb[t_][1].w, RP2[7])                         \
    CELL(RP1[5], RP2[5], RP1[6], cb[t_][1].z, RP2[6])                         \
    CELL(RP1[4], RP2[4], RP1[5], cb[t_][1].y, RP2[5])                         \
    CELL(RP1[3], RP2[3], RP1[4], cb[t_][1].x, RP2[4])                         \
    CELL(RP1[2], RP2[2], RP1[3], cb[t_][0].w, RP2[3])                         \
    CELL(RP1[1], RP2[1], RP1[2], cb[t_][0].z, RP2[2])                         \
    CELL(RP1[0], RP2[0], RP1[1], cb[t_][0].y, RP2[1])                         \
    CELL(up0,    dg0,    RP1[0], cb[t_][0].x, RP2[0])                         \
  }

#define FILL(sn_)                                                             \
  {                                                                           \
    const int sn = (sn_);                                                     \
    if (sn < NSS) {                                                           \
      const int d0n = 2 + SS * sn;                                            \
      const int hb2 = (sn & 1) * (SS * T);                                    \
      for (int t = wave - 1; t < SS; t += 4) {                                \
        const int d = d0n + t;                                                \
        const int lo = (d <= T + 1) ? 1 : d - T;                              \
        const int hi = (d - 1 < T) ? d - 1 : T;                               \
        const int off = (d <= T + 1)                                          \
            ? (((d - 2) * (d - 1)) >> 1)                                      \
            : (T * T - (((2 * T + 1 - d) * (2 * T + 2 - d)) >> 1));           \
        float* dst = &lds[hb2 + t * T];                                       \
        _Pragma("unroll")                                                     \
        for (int u = 0; u < 8; ++u) {                                         \
          const int idx = (u << 6) + lane;                                    \
          const int row = idx + 1;                                            \
          int src = off + row - lo;                                           \
          src = (src < 0) ? 0 : src;                                          \
          src = (src > T * T - 1) ? (T * T - 1) : src;                        \
          dst[idx] = (row >= lo && row <= hi) ? Db[src] : BIGF;               \
        }                                                                     \
      }                                                                       \
    }                                                                         \
  }

__global__ __launch_bounds__(320, 1) void dp_ring_kernel(const float* __restrict__ D,
                                                         float* __restrict__ out) {
  const int b = blockIdx.x;
  const int tid = threadIdx.x;
  const int wave = tid >> 6;   // 0 = consumer, 1..4 = producers
  const int lane = tid & 63;
  const bool lz = (lane == 0);
  const float* __restrict__ Db = D + (size_t)b * (T * T);
#if !__has_builtin(__builtin_amdgcn_update_dpp)
  const int rot_addr = ((lane + 63) & 63) << 2;
#endif

  __shared__ float lds[2 * SS * T];  // 64 KB double-buffered ring

  float A[8], Bv[8];
  #pragma unroll
  for (int k = 0; k < 8; ++k) { A[k] = BIGF; Bv[k] = BIGF; }

  if (wave > 0) FILL(0)
  __syncthreads();

  #pragma unroll 1
  for (int s = 0; s < NSS; ++s) {
    if (wave == 0) {
      const float dseed = (s == 0) ? 0.0f : BIGF;  // R[0][0]=0 enters at d==2
      const float* hb = &lds[(s & 1) * (SS * T) + (lane << 3)];
      float4 cb[16][2];
      #pragma unroll
      for (int t = 0; t < 16; ++t) {
        const float4* cp = (const float4*)(hb + t * T);
        cb[t][0] = cp[0];
        cb[t][1] = cp[1];
      }
      #pragma unroll
      for (int t = 0; t < 16; t += 2) {
        DTWSTEP(t,     A,  Bv)   // even diag -> writes A
        DTWSTEP(t + 1, Bv, A)    // odd diag  -> writes Bv
      }
    } else {
      FILL(s + 1)
    }
    __syncthreads();
  }

  // R'(512,512): diag 1024 (even) -> A; row 512 = lane 63, slot 7.
  if (tid == 63) atomicAdd(out, A[7] * (LN2f / BATCH));
}

// ---------------------------------------------------------------------------
// Fallback (ws too small): fused on-the-fly DP (round-2 version, known good).
// ---------------------------------------------------------------------------
__global__ __launch_bounds__(512) void dp_onfly_kernel(
    const float* __restrict__ x, const float* __restrict__ y,
    float* __restrict__ out) {
  int b = blockIdx.x;
  int tid = threadIdx.x;
  int i = tid + 1;

  __shared__ float ys[T][DIMS + 1];
  __shared__ float y2s[T];
  __shared__ float rbuf[3][T + 1];

  const float* yb = y + (size_t)b * T * DIMS;
  for (int e = tid; e < T * DIMS; e += 512) {
    int r = e >> 6, c = e & 63;
    ys[r][c] = yb[e];
  }
  for (int e = tid; e < 3 * (T + 1); e += 512) ((float*)rbuf)[e] = BIGF;
  __syncthreads();
  if (tid == 0) rbuf[0][0] = 0.f;
  {
    float s = 0.f;
    #pragma unroll
    for (int k = 0; k < DIMS; ++k) { float v = ys[tid][k]; s += v * v; }
    y2s[tid] = s;
  }

  float xr[DIMS];
  float x2 = 0.f;
  const float* xb = x + ((size_t)b * T + (i - 1)) * DIMS;
  #pragma unroll
  for (int k = 0; k < DIMS; ++k) { xr[k] = xb[k]; x2 += xr[k] * xr[k]; }
  __syncthreads();

  float* rp2 = rbuf[0];
  float* rp1 = rbuf[1];
  float* rc  = rbuf[2];

  float val = BIGF;
  for (int d = 2; d <= 2 * T; ++d) {
    int j = d - i;
    bool valid = (j >= 1) && (j <= T);
    float cost = 0.f;
    if (valid) {
      float dot = 0.f;
      #pragma unroll
      for (int k = 0; k < DIMS; ++k) dot += xr[k] * ys[j - 1][k];
      cost = x2 + y2s[j - 1] - 2.f * dot;
    }
    float a = rp1[i - 1];
    float bb = rp1[i];
    float c = rp2[i - 1];
    float m = fminf(fminf(a, bb), c);
    float s = __expf(m - a) + __expf(m - bb) + __expf(m - c);
    val = valid ? (cost + m - __logf(s)) : BIGF;
    rc[i] = val;
    if (tid == 0) rc[0] = BIGF;
    __syncthreads();
    float* tmp = rp2; rp2 = rp1; rp1 = rc; rc = tmp;
  }

  if (tid == T - 1) atomicAdd(out, val * (1.0f / BATCH));
}

extern "C" void kernel_launch(void* const* d_in, const int* in_sizes, int n_in,
                              void* d_out, int out_size, void* d_ws, size_t ws_size,
                              hipStream_t stream) {
  const float* x = (const float*)d_in[0];   // inputs  (B,T,D)
  const float* y = (const float*)d_in[1];   // targets (B,T,D)
  float* out = (float*)d_out;

  hipMemsetAsync(d_out, 0, sizeof(float), stream);

  size_t needD = (size_t)BATCH * T * T * sizeof(float);  // 64 MiB
  if (ws_size >= needD) {
    float* Dw = (float*)d_ws;
    pairdist_diag_kernel<<<BATCH * 64, 256, 0, stream>>>(x, y, Dw);
    dp_ring_kernel<<<BATCH, 320, 0, stream>>>(Dw, out);
  } else {
    dp_onfly_kernel<<<BATCH, 512, 0, stream>>>(x, y, out);
  }
}